// Round 3
// baseline (579.286 us; speedup 1.0000x reference)
//
#include <hip/hip_runtime.h>
#include <math.h>

#define L_SEQ 1024
#define DM 128
#define JC 64
#define NCH (L_SEQ / JC)

// workspace layout (floats)
#define OFF_KHAT 0                         // [L][4][48]  slots: 0..31 K, 32..43 Kg, 44 ck, 45 1.0, 46..47 0
#define OFF_QHAT (L_SEQ * 192)             // [L][4][48]  slots: 0..31 scale*Q, 32..43 w*Qg, 44 1.0, 45 cq
#define OFF_V    (OFF_QHAT + L_SEQ * 192)  // [L][128]    (h*32+d)
#define OFF_VG   (OFF_V + L_SEQ * DM)      // [L][48]     (h*12+p*3+x)

typedef __attribute__((address_space(1))) const void* gas_t;
typedef __attribute__((address_space(3))) void* las_t;

__device__ __forceinline__ void async16(const float4* g, float4* l) {
    __builtin_amdgcn_global_load_lds((gas_t)g, (las_t)l, 16, 0, 0);
}
// raw barrier: drain LDS ops only; do NOT drain vmcnt (keeps async prefetch in flight)
#define ASYNC_BAR() asm volatile("s_waitcnt lgkmcnt(0)\n\ts_barrier" ::: "memory")
#define MEMBAR()    asm volatile("" ::: "memory")

// ---------------- kernel 1: LN + projections + rotations + staging ----------------
__global__ __launch_bounds__(256) void ipa_prep(
    const float* __restrict__ single, const float* __restrict__ T,
    const float* __restrict__ w_C, const float* __restrict__ ln_g, const float* __restrict__ ln_b,
    const float* __restrict__ Wq, const float* __restrict__ Wk, const float* __restrict__ Wv,
    const float* __restrict__ Wqpt, const float* __restrict__ Wkpt, const float* __restrict__ Wvpt,
    float* __restrict__ ws)
{
    __shared__ float z_lds[4][128];
    __shared__ float proj[4][528];
    __shared__ float qg[4][4][4][3];
    __shared__ float kg[4][4][4][3];
    __shared__ float cq[4][4], ck[4][4];

    const int t = threadIdx.x;
    const int wv = t >> 6, lane = t & 63;
    const int i0 = blockIdx.x << 2;
    const int i = i0 + wv;

    float x0 = single[i*DM + lane];
    float x1 = single[i*DM + 64 + lane];
    float s = x0 + x1, s2 = x0*x0 + x1*x1;
    #pragma unroll
    for (int off = 1; off < 64; off <<= 1) { s += __shfl_xor(s, off); s2 += __shfl_xor(s2, off); }
    float mu = s * 0.0078125f;
    float var = s2 * 0.0078125f - mu*mu;
    float rs = rsqrtf(var + 1e-5f);
    z_lds[wv][lane]      = (x0 - mu) * rs * ln_g[lane]      + ln_b[lane];
    z_lds[wv][lane + 64] = (x1 - mu) * rs * ln_g[lane + 64] + ln_b[lane + 64];
    __syncthreads();

    for (int cc = t; cc < 528; cc += 256) {
        const float* W; int col, ncol;
        if (cc < 128)      { W = Wq;   col = cc;       ncol = 128; }
        else if (cc < 256) { W = Wk;   col = cc - 128; ncol = 128; }
        else if (cc < 384) { W = Wv;   col = cc - 256; ncol = 128; }
        else if (cc < 432) { W = Wqpt; col = cc - 384; ncol = 48;  }
        else if (cc < 480) { W = Wkpt; col = cc - 432; ncol = 48;  }
        else               { W = Wvpt; col = cc - 480; ncol = 48;  }
        float a0 = 0.f, a1 = 0.f, a2 = 0.f, a3 = 0.f;
        #pragma unroll 8
        for (int k = 0; k < 128; ++k) {
            float w = W[k*ncol + col];
            a0 = fmaf(z_lds[0][k], w, a0);
            a1 = fmaf(z_lds[1][k], w, a1);
            a2 = fmaf(z_lds[2][k], w, a2);
            a3 = fmaf(z_lds[3][k], w, a3);
        }
        proj[0][cc] = a0; proj[1][cc] = a1; proj[2][cc] = a2; proj[3][cc] = a3;
    }
    __syncthreads();

    if (t < 64) {
        int r = t >> 4, h = (t >> 2) & 3, p = t & 3;
        int ii = i0 + r;
        float R[3][3], tt[3];
        #pragma unroll
        for (int x = 0; x < 3; ++x) {
            #pragma unroll
            for (int y = 0; y < 3; ++y) R[x][y] = T[ii*16 + x*4 + y];
            tt[x] = T[ii*16 + x*4 + 3];
        }
        int base = 384 + (h*4 + p)*3;
        float q0 = proj[r][base],    q1 = proj[r][base+1],  q2 = proj[r][base+2];
        float k0 = proj[r][base+48], k1 = proj[r][base+49], k2 = proj[r][base+50];
        float v0 = proj[r][base+96], v1 = proj[r][base+97], v2 = proj[r][base+98];
        #pragma unroll
        for (int x = 0; x < 3; ++x) {
            float qq = R[x][0]*q0 + R[x][1]*q1 + R[x][2]*q2 + tt[x];
            float kk = R[x][0]*k0 + R[x][1]*k1 + R[x][2]*k2 + tt[x];
            float vv = R[x][0]*v0 + R[x][1]*v1 + R[x][2]*v2 + tt[x];
            qg[r][h][p][x] = qq;
            kg[r][h][p][x] = kk;
            ws[OFF_VG + ii*48 + h*12 + p*3 + x] = vv;
        }
    }
    __syncthreads();

    if (t < 32) {
        int r = t >> 3, h = (t >> 1) & 3, isk = t & 1;
        float w = w_C[h];
        float wp = log1pf(__expf(w));
        float sq = 0.f;
        #pragma unroll
        for (int p = 0; p < 4; ++p)
            #pragma unroll
            for (int x = 0; x < 3; ++x) {
                float g = isk ? kg[r][h][p][x] : qg[r][h][p][x];
                sq += g*g;
            }
        float c = -0.5f * wp * sq;
        if (isk) ck[r][h] = c; else cq[r][h] = c;
    }
    __syncthreads();

    for (int idx = t; idx < 512; idx += 256) {
        int r = idx >> 7, d = idx & 127;
        ws[OFF_V + (size_t)(i0 + r)*DM + d] = proj[r][256 + d];
    }
    const float scale_attn = 0.17677669529663687f;  // 32^-0.5
    for (int idx = t; idx < 768; idx += 256) {
        int r = idx / 192, rem = idx % 192;
        int h = rem / 48, k = rem % 48;
        int ii = i0 + r;
        float w = w_C[h];
        float wp = log1pf(__expf(w));
        float kv, qv;
        if (k < 32) {
            kv = proj[r][128 + h*32 + k];
            qv = scale_attn * proj[r][h*32 + k];
        } else if (k < 44) {
            int e = k - 32;
            kv = kg[r][h][e/3][e%3];
            qv = wp * qg[r][h][e/3][e%3];
        } else if (k == 44) { kv = ck[r][h]; qv = 1.0f; }
        else if (k == 45)   { kv = 1.0f;    qv = cq[r][h]; }
        else                { kv = 0.f;     qv = 0.f; }
        ws[OFF_KHAT + (size_t)ii*192 + h*48 + k] = kv;
        ws[OFF_QHAT + (size_t)ii*192 + h*48 + k] = qv;
    }
}

// ---------------- kernel 2: fused IPA attention, 1 row/block, 4 blocks/CU ----------------
__global__ __launch_bounds__(256, 4) void ipa_attn(
    const float* __restrict__ single, const float* __restrict__ pair,
    const float* __restrict__ T, const float* __restrict__ Wb,
    const float* __restrict__ Wout, const float* __restrict__ b_out,
    const float* __restrict__ ws, float* __restrict__ out)
{
    __shared__ __align__(16) float4 pair_s[2][JC][16];  // 32768 B, slot = c4 ^ (j&7)
    __shared__ float bias_s[16][JC];                    // [cq*4+h][j]  4096 B
    __shared__ float p_s[4][JC];                        // [h][j]       1024 B
    __shared__ __align__(16) float4 qhat_s[48];         // [h*12+k4]     768 B
    __shared__ __align__(16) float4 wb_s[64];           // Wb rows      1024 B
    __shared__ float l_s[4];
    __shared__ float alpha_s[4];
    // total 39.7 KB -> 4 blocks/CU

    const int t = threadIdx.x;
    const int wv = t >> 6, lane = t & 63;
    const int i = blockIdx.x;

    // stage qhat + Wb (before asyncs so their implicit vmcnt drains don't touch asyncs)
    if (t < 48)       qhat_s[t]    = ((const float4*)(ws + OFF_QHAT))[(size_t)i*48 + t];
    else if (t < 112) wb_s[t - 48] = ((const float4*)Wb)[t - 48];
    MEMBAR();

    float m_run = -INFINITY, l_run = 0.f;
    float4 accp[4], accs, accg;
    accs = make_float4(0.f,0.f,0.f,0.f);
    accg = make_float4(0.f,0.f,0.f,0.f);
    #pragma unroll
    for (int h = 0; h < 4; ++h) accp[h] = make_float4(0.f,0.f,0.f,0.f);

    const float4* pair4 = (const float4*)pair;
    const float4* kh4   = (const float4*)(ws + OFF_KHAT);
    const float4* v4    = (const float4*)(ws + OFF_V);
    const float4* vg4   = (const float4*)(ws + OFF_VG);
    float4* pbase = &pair_s[0][0][0];

    // lane roles
    const int d4  = lane & 7,  jg7 = lane >> 3;   // o_s
    const int c4p = lane >> 4, jgp = lane & 15;   // o_pair
    const int g4  = lane & 3,  jg4 = lane >> 2;   // o_pt_g
    const int g4c = (g4 < 3) ? g4 : 0;

    // issue chunk 0 -> buf 0
    #pragma unroll
    for (int it = 0; it < 4; ++it) {
        int idx = it*256 + t;
        int j = idx >> 4, slot = idx & 15;
        async16(pair4 + ((size_t)i*L_SEQ + j)*16 + (slot ^ (j & 7)), pbase + idx);
    }

    for (int ch = 0; ch < NCH; ++ch) {
        const int cur = ch & 1;
        const int j0  = ch * JC;

        ASYNC_BAR();   // everyone done reading buf[1-cur] (prev accumulate); asyncs(ch) already drained

        // kh for THIS chunk, issued BEFORE next asyncs (FIFO: consuming kh won't drain them)
        float4 khr[12];
        {
            const float4* kp = kh4 + (size_t)(j0 + lane)*48 + wv*12;
            #pragma unroll
            for (int k4 = 0; k4 < 12; ++k4) khr[k4] = kp[k4];
        }
        MEMBAR();
        if (ch + 1 < NCH) {
            const int jn = j0 + JC;
            #pragma unroll
            for (int it = 0; it < 4; ++it) {
                int idx = it*256 + t;
                int j = idx >> 4, slot = idx & 15;
                async16(pair4 + ((size_t)i*L_SEQ + jn + j)*16 + (slot ^ (j & 7)),
                        pbase + (1 - cur)*1024 + idx);
            }
        }
        if (ch == 0)
            asm volatile("s_waitcnt vmcnt(16)" ::: "memory");  // drain initial asyncs(0); keep khr(12)+asyncs(1)(4)
        ASYNC_BAR();   // buf[cur] visible

        // ---- bias partials: lane=j, wave wv covers c-quarter [16wv,16wv+16) for all heads ----
        {
            float b0=0.f, b1=0.f, b2=0.f, b3=0.f;
            #pragma unroll
            for (int k = 0; k < 4; ++k) {
                float4 pv = pair_s[cur][lane][(wv*4 + k) ^ (lane & 7)];
                float4 w0 = wb_s[wv*16 + k*4 + 0], w1 = wb_s[wv*16 + k*4 + 1];
                float4 w2 = wb_s[wv*16 + k*4 + 2], w3 = wb_s[wv*16 + k*4 + 3];
                b0 += pv.x*w0.x + pv.y*w1.x + pv.z*w2.x + pv.w*w3.x;
                b1 += pv.x*w0.y + pv.y*w1.y + pv.z*w2.y + pv.w*w3.y;
                b2 += pv.x*w0.z + pv.y*w1.z + pv.z*w2.z + pv.w*w3.z;
                b3 += pv.x*w0.w + pv.y*w1.w + pv.z*w2.w + pv.w*w3.w;
            }
            bias_s[wv*4 + 0][lane] = b0; bias_s[wv*4 + 1][lane] = b1;
            bias_s[wv*4 + 2][lane] = b2; bias_s[wv*4 + 3][lane] = b3;
        }
        ASYNC_BAR();   // bias partials visible

        // ---- softmax: lane=j, head wv; consume khr ----
        float my_alpha;
        {
            float d = 0.f;
            #pragma unroll
            for (int k4 = 0; k4 < 12; ++k4) {
                float4 q = qhat_s[wv*12 + k4];
                d = fmaf(khr[k4].x, q.x, d); d = fmaf(khr[k4].y, q.y, d);
                d = fmaf(khr[k4].z, q.z, d); d = fmaf(khr[k4].w, q.w, d);
            }
            float bias = bias_s[0*4 + wv][lane] + bias_s[1*4 + wv][lane]
                       + bias_s[2*4 + wv][lane] + bias_s[3*4 + wv][lane];
            float logit = d + bias;
            float cmax = logit;
            #pragma unroll
            for (int off = 1; off < 64; off <<= 1) cmax = fmaxf(cmax, __shfl_xor(cmax, off));
            float mn = fmaxf(m_run, cmax);
            my_alpha = __expf(m_run - mn);
            float pj = __expf(logit - mn);
            float ps = pj;
            #pragma unroll
            for (int off = 1; off < 64; off <<= 1) ps += __shfl_xor(ps, off);
            l_run = l_run * my_alpha + ps;
            m_run = mn;
            p_s[wv][lane] = pj;
            if (lane == 0) alpha_s[wv] = my_alpha;
        }
        ASYNC_BAR();   // p + alpha visible

        // ---- accumulate ----
        {
            // batch-issue the global V/Vg loads up front (consumption drains asyncs(ch+1)
            // only after bias+softmax flight time)
            float4 vvr[8];
            #pragma unroll
            for (int jj = 0; jj < 8; ++jj)
                vvr[jj] = v4[(size_t)(j0 + jg7 + 8*jj)*32 + wv*8 + d4];
            float4 gvr[4];
            #pragma unroll
            for (int jj = 0; jj < 4; ++jj)
                gvr[jj] = vg4[(size_t)(j0 + jg4 + 16*jj)*12 + wv*3 + g4c];

            float a0 = alpha_s[0], a1 = alpha_s[1], a2 = alpha_s[2], a3 = alpha_s[3];
            accp[0].x *= a0; accp[0].y *= a0; accp[0].z *= a0; accp[0].w *= a0;
            accp[1].x *= a1; accp[1].y *= a1; accp[1].z *= a1; accp[1].w *= a1;
            accp[2].x *= a2; accp[2].y *= a2; accp[2].z *= a2; accp[2].w *= a2;
            accp[3].x *= a3; accp[3].y *= a3; accp[3].z *= a3; accp[3].w *= a3;
            accs.x *= my_alpha; accs.y *= my_alpha; accs.z *= my_alpha; accs.w *= my_alpha;
            accg.x *= my_alpha; accg.y *= my_alpha; accg.z *= my_alpha; accg.w *= my_alpha;

            // o_pair: c4 = wv*4 + c4p for all heads
            const int c4 = wv*4 + c4p;
            #pragma unroll
            for (int jj = 0; jj < 4; ++jj) {
                int j = jgp + 16*jj;
                float4 pv = pair_s[cur][j][c4 ^ (j & 7)];
                float p0 = p_s[0][j], p1 = p_s[1][j], p2 = p_s[2][j], p3 = p_s[3][j];
                accp[0].x = fmaf(p0, pv.x, accp[0].x); accp[0].y = fmaf(p0, pv.y, accp[0].y);
                accp[0].z = fmaf(p0, pv.z, accp[0].z); accp[0].w = fmaf(p0, pv.w, accp[0].w);
                accp[1].x = fmaf(p1, pv.x, accp[1].x); accp[1].y = fmaf(p1, pv.y, accp[1].y);
                accp[1].z = fmaf(p1, pv.z, accp[1].z); accp[1].w = fmaf(p1, pv.w, accp[1].w);
                accp[2].x = fmaf(p2, pv.x, accp[2].x); accp[2].y = fmaf(p2, pv.y, accp[2].y);
                accp[2].z = fmaf(p2, pv.z, accp[2].z); accp[2].w = fmaf(p2, pv.w, accp[2].w);
                accp[3].x = fmaf(p3, pv.x, accp[3].x); accp[3].y = fmaf(p3, pv.y, accp[3].y);
                accp[3].z = fmaf(p3, pv.z, accp[3].z); accp[3].w = fmaf(p3, pv.w, accp[3].w);
            }
            // o_s: head wv
            #pragma unroll
            for (int jj = 0; jj < 8; ++jj) {
                int j = jg7 + 8*jj;
                float pw = p_s[wv][j];
                accs.x = fmaf(pw, vvr[jj].x, accs.x); accs.y = fmaf(pw, vvr[jj].y, accs.y);
                accs.z = fmaf(pw, vvr[jj].z, accs.z); accs.w = fmaf(pw, vvr[jj].w, accs.w);
            }
            // o_pt_g: head wv
            #pragma unroll
            for (int jj = 0; jj < 4; ++jj) {
                int j = jg4 + 16*jj;
                float pw = p_s[wv][j];
                accg.x = fmaf(pw, gvr[jj].x, accg.x); accg.y = fmaf(pw, gvr[jj].y, accg.y);
                accg.z = fmaf(pw, gvr[jj].z, accg.z); accg.w = fmaf(pw, gvr[jj].w, accg.w);
            }
        }
    }

    // ---- epilogue: reductions ----
    #pragma unroll
    for (int h = 0; h < 4; ++h) {
        #pragma unroll
        for (int off = 1; off < 16; off <<= 1) {      // reduce over jgp
            accp[h].x += __shfl_xor(accp[h].x, off);
            accp[h].y += __shfl_xor(accp[h].y, off);
            accp[h].z += __shfl_xor(accp[h].z, off);
            accp[h].w += __shfl_xor(accp[h].w, off);
        }
    }
    #pragma unroll
    for (int off = 8; off < 64; off <<= 1) {          // reduce over jg7
        accs.x += __shfl_xor(accs.x, off); accs.y += __shfl_xor(accs.y, off);
        accs.z += __shfl_xor(accs.z, off); accs.w += __shfl_xor(accs.w, off);
    }
    #pragma unroll
    for (int off = 4; off < 64; off <<= 1) {          // reduce over jg4
        accg.x += __shfl_xor(accg.x, off); accg.y += __shfl_xor(accg.y, off);
        accg.z += __shfl_xor(accg.z, off); accg.w += __shfl_xor(accg.w, off);
    }
    if (lane == 0) l_s[wv] = l_run;
    __syncthreads();   // full barrier: all waves done with pair_s; l_s visible -> safe to alias

    float* u    = (float*)pair_s;       // u[0..447]
    float* psum = u + 512;              // psum[2][128]
    float* og   = u + 1024;             // og[4*12]
    const float invw = 1.f / l_run;     // own head's normalizer (uniform in wave)

    if (lane < 8) {
        int base = wv*32 + lane*4;
        u[base+0] = accs.x*invw; u[base+1] = accs.y*invw;
        u[base+2] = accs.z*invw; u[base+3] = accs.w*invw;
    }
    if (jgp == 0) {
        int c4 = wv*4 + c4p;
        float il0 = 1.f/l_s[0], il1 = 1.f/l_s[1], il2 = 1.f/l_s[2], il3 = 1.f/l_s[3];
        int b0 = 128 + 0*64 + c4*4, b1 = 128 + 1*64 + c4*4, b2 = 128 + 2*64 + c4*4, b3 = 128 + 3*64 + c4*4;
        u[b0+0] = accp[0].x*il0; u[b0+1] = accp[0].y*il0; u[b0+2] = accp[0].z*il0; u[b0+3] = accp[0].w*il0;
        u[b1+0] = accp[1].x*il1; u[b1+1] = accp[1].y*il1; u[b1+2] = accp[1].z*il1; u[b1+3] = accp[1].w*il1;
        u[b2+0] = accp[2].x*il2; u[b2+1] = accp[2].y*il2; u[b2+2] = accp[2].z*il2; u[b2+3] = accp[2].w*il2;
        u[b3+0] = accp[3].x*il3; u[b3+1] = accp[3].y*il3; u[b3+2] = accp[3].z*il3; u[b3+3] = accp[3].w*il3;
    }
    if (lane < 3) {
        og[wv*12 + lane*4 + 0] = accg.x*invw; og[wv*12 + lane*4 + 1] = accg.y*invw;
        og[wv*12 + lane*4 + 2] = accg.z*invw; og[wv*12 + lane*4 + 3] = accg.w*invw;
    }
    __syncthreads();

    // inverse-rotate o_pt_g, norms
    if (t < 16) {
        int h = t >> 2, p = t & 3;
        float R[3][3], tt[3];
        #pragma unroll
        for (int x = 0; x < 3; ++x) {
            #pragma unroll
            for (int y = 0; y < 3; ++y) R[x][y] = T[i*16 + x*4 + y];
            tt[x] = T[i*16 + x*4 + 3];
        }
        float v0 = og[h*12 + p*3 + 0] - tt[0];
        float v1 = og[h*12 + p*3 + 1] - tt[1];
        float v2 = og[h*12 + p*3 + 2] - tt[2];
        float n2 = 0.f;
        #pragma unroll
        for (int x = 0; x < 3; ++x) {
            float o = R[0][x]*v0 + R[1][x]*v1 + R[2][x]*v2;
            u[384 + h*12 + p*3 + x] = o;
            n2 += o*o;
        }
        u[432 + h*4 + p] = sqrtf(n2);
    }
    __syncthreads();

    // final projection: out = single + u @ Wout + b_out (k-split over 2 half-blocks)
    {
        int part = t >> 7, d = t & 127;
        float acc = part ? 0.f : (single[i*DM + d] + b_out[d]);
        const float4* u4 = (const float4*)u;
        #pragma unroll 4
        for (int k4 = part*56; k4 < part*56 + 56; ++k4) {
            float4 uv = u4[k4];
            const float* wp = Wout + (size_t)(k4*4)*128 + d;
            acc = fmaf(uv.x, wp[0],   acc);
            acc = fmaf(uv.y, wp[128], acc);
            acc = fmaf(uv.z, wp[256], acc);
            acc = fmaf(uv.w, wp[384], acc);
        }
        psum[part*128 + d] = acc;
    }
    __syncthreads();
    if (t < 128) out[i*DM + t] = psum[t] + psum[128 + t];
}

extern "C" void kernel_launch(void* const* d_in, const int* in_sizes, int n_in,
                              void* d_out, int out_size, void* d_ws, size_t ws_size,
                              hipStream_t stream)
{
    const float* single = (const float*)d_in[0];
    const float* pair   = (const float*)d_in[1];
    const float* T      = (const float*)d_in[2];
    const float* w_C    = (const float*)d_in[3];
    const float* ln_g   = (const float*)d_in[4];
    const float* ln_b   = (const float*)d_in[5];
    const float* Wq     = (const float*)d_in[6];
    const float* Wk     = (const float*)d_in[7];
    const float* Wv     = (const float*)d_in[8];
    const float* Wqpt   = (const float*)d_in[9];
    const float* Wkpt   = (const float*)d_in[10];
    const float* Wvpt   = (const float*)d_in[11];
    const float* Wb     = (const float*)d_in[12];
    const float* Wout   = (const float*)d_in[13];
    const float* b_out  = (const float*)d_in[14];
    float* out = (float*)d_out;
    float* ws  = (float*)d_ws;

    ipa_prep<<<256, 256, 0, stream>>>(single, T, w_C, ln_g, ln_b, Wq, Wk, Wv, Wqpt, Wkpt, Wvpt, ws);
    ipa_attn<<<1024, 256, 0, stream>>>(single, pair, T, Wb, Wout, b_out, ws, out);
}